// Round 15
// baseline (337.867 us; speedup 1.0000x reference)
//
#include <hip/hip_runtime.h>
#include <math.h>

namespace {

typedef unsigned short u16;
typedef __attribute__((ext_vector_type(8))) short short8;   // 8 bf16 = 4 VGPRs
typedef __attribute__((ext_vector_type(4))) float f32x4;
typedef __attribute__((ext_vector_type(16))) float f32x16;

constexpr int kDim   = 1152;
constexpr int kHeads = 9;
constexpr int kMid   = 256;
constexpr int kB     = 8;
constexpr int kN     = 1024;
constexpr int kM     = kB * kN;                 // 8192 tokens
constexpr int kQS    = 3584;                    // padded qkv row stride (14*256)
constexpr float kCexp  = 0.12753837360881433f;  // 128^-0.5 * log2(e), folded into Wq

__device__ __forceinline__ u16 f2bf(float f) {
    unsigned u = __builtin_bit_cast(unsigned, f);
    return (u16)((u + 0x7FFFu + ((u >> 16) & 1u)) >> 16);
}
__device__ __forceinline__ float bf2f(u16 h) {
    unsigned u = ((unsigned)h) << 16;
    return __builtin_bit_cast(float, u);
}

// async global->LDS, 16B/lane. dst wave-uniform; lane i lands at dst + i*16.
__device__ __forceinline__ void gload_lds16(const void* g, void* l) {
    __builtin_amdgcn_global_load_lds(
        (const __attribute__((address_space(1))) unsigned int*)g,
        (__attribute__((address_space(3))) unsigned int*)l,
        16, 0, 0);
}

__device__ __forceinline__ unsigned cvtpk(float a, float b) {
    unsigned r;
    asm volatile("v_cvt_pk_bf16_f32 %0, %1, %2" : "=v"(r) : "v"(a), "v"(b));
    return r;  // lo16 = bf16(a), hi16 = bf16(b)
}

// exchange: x' = [x_lo, y_lo(partner)], y' = [x_hi(partner), y_hi]
__device__ __forceinline__ void halfswap(unsigned& x, unsigned& y, bool hihalf) {
    const unsigned xs = (unsigned)__shfl_xor((int)x, 32);
    const unsigned ys = (unsigned)__shfl_xor((int)y, 32);
    const unsigned nx = hihalf ? ys : x;
    const unsigned ny = hihalf ? y : xs;
    x = nx; y = ny;
}

__device__ __forceinline__ short8 build_pfrag(float p0, float p1, float p2, float p3,
                                              float p4, float p5, float p6, float p7,
                                              bool hihalf) {
    unsigned x1 = cvtpk(p0, p1), y1 = cvtpk(p4, p5);
    unsigned x2 = cvtpk(p2, p3), y2 = cvtpk(p6, p7);
    halfswap(x1, y1, hihalf);
    halfswap(x2, y2, hihalf);
    union { unsigned u[4]; short8 s; } pk;
    pk.u[0] = x1; pk.u[1] = x2; pk.u[2] = y1; pk.u[3] = y2;
    return pk.s;
}

// ---------------------------------------------------------------------------
// One fused prep kernel. Wqkv q-rows scaled by kCexp in f32 before bf16
// conversion (softmax scale folded into Q — exact linearity).
// ---------------------------------------------------------------------------
constexpr int R0 = 2359296;            // x            [8192*1152/4]
constexpr int R1 = R0 + 995328;        // Wqkv         [3456*1152/4]
constexpr int R2 = R1 + 331776;        // Wproj        [1152*1152/4]
constexpr int R3 = R2 + 73728;         // down_w       [256*1152/4]
constexpr int R4 = R3 + 73728;         // pdown_w
constexpr int R5 = R4 + 147456;        // up_w         [2304*256/4] strided
constexpr int R6 = R5 + 147456;        // pup_w        strided
constexpr int R7 = R6 + 512;           // bd scalars
constexpr int R8 = R7 + 2304;          // bu scalars
constexpr int kQPart = 331776;         // Wqkv q-part float4 count (1152*1152/4)
constexpr int kPrepGrid = R8 / 256;    // 16139 exactly

__global__ __launch_bounds__(256)
void prep_all(const float* __restrict__ x, const float* __restrict__ Wqkv,
              const float* __restrict__ Wproj,
              const float* __restrict__ down_w, const float* __restrict__ pdown_w,
              const float* __restrict__ up_w, const float* __restrict__ pup_w,
              const float* __restrict__ down_b, const float* __restrict__ pdown_b,
              const float* __restrict__ up_b, const float* __restrict__ pup_b,
              const int* __restrict__ task,
              u16* __restrict__ xb, u16* __restrict__ wqkvb, u16* __restrict__ wprjb,
              u16* __restrict__ wdownb, u16* __restrict__ wupb,
              float* __restrict__ bd, float* __restrict__ bu)
{
    const int i = blockIdx.x * blockDim.x + threadIdx.x;
    auto cvt4s = [](const float* s, int j, float sc) {
        const float4 v = reinterpret_cast<const float4*>(s)[j];
        ushort4 o;
        o.x = f2bf(v.x * sc); o.y = f2bf(v.y * sc);
        o.z = f2bf(v.z * sc); o.w = f2bf(v.w * sc);
        return o;
    };
    if (i < R0) {
        reinterpret_cast<ushort4*>(xb)[i] = cvt4s(x, i, 1.f);
    } else if (i < R1) {
        const int j = i - R0;
        const float sc = (j < kQPart) ? kCexp : 1.f;   // fold softmax scale into Wq
        reinterpret_cast<ushort4*>(wqkvb)[j] = cvt4s(Wqkv, j, sc);
    } else if (i < R2) {
        reinterpret_cast<ushort4*>(wprjb)[i - R1] = cvt4s(Wproj, i - R1, 1.f);
    } else if (i < R3) {
        reinterpret_cast<ushort4*>(wdownb)[i - R2] = cvt4s(down_w, i - R2, 1.f);
    } else if (i < R4) {
        reinterpret_cast<ushort4*>(wdownb)[73728 + (i - R3)] = cvt4s(pdown_w, i - R3, 1.f);
    } else if (i < R5) {
        const int j = i - R4, r = j >> 6, c = j & 63;
        reinterpret_cast<ushort4*>(wupb)[r * 128 + c] = cvt4s(up_w, j, 1.f);
    } else if (i < R6) {
        const int j = i - R5, r = j >> 6, c = j & 63;
        reinterpret_cast<ushort4*>(wupb)[r * 128 + 64 + c] = cvt4s(pup_w, j, 1.f);
    } else if (i < R7) {
        const int j = i - R6;
        bd[j] = (j < 256) ? down_b[j] : pdown_b[j - 256];
    } else {
        const int j = i - R7;
        bu[j] = up_b[j] + ((*task >= 5) ? pup_b[j] : 0.f);
    }
}

// ---------------------------------------------------------------------------
// 256x256 tile GEMM, 8-phase template (T3+T4). qkv only (r13 configuration).
// ---------------------------------------------------------------------------
template<bool ACCUM, bool BIAS>
__global__ __launch_bounds__(512, 2)
void gemm8p(const u16* __restrict__ A, const u16* __restrict__ Bw,
            const float* __restrict__ bias, u16* __restrict__ C,
            int K, int lda, int ldb, int ldc)
{
    extern __shared__ char lds[];   // [A0 32K][A1 32K][B0 32K][B1 32K]

    const int tid  = threadIdx.x;
    const int lane = tid & 63;
    const int wid  = tid >> 6;
    const int wm   = wid >> 2;             // 0..1 : 128-row half
    const int wn   = wid & 3;              // 0..3 : 64-col quarter
    const int bm   = blockIdx.x * 256;
    const int bn   = blockIdx.y * 256;
    const int l15  = lane & 15;
    const int kq   = lane >> 4;            // 0..3

    int srow[4], scol[4], sdst[4];
#pragma unroll
    for (int i = 0; i < 4; ++i) {
        const int id = i * 512 + tid;
        srow[i] = id >> 3;
        const int s = id & 7;
        scol[i] = (s ^ (srow[i] & 7)) * 8;          // pre-swizzled source col (elems)
        sdst[i] = (i * 512 + wid * 64) * 16;        // wave-uniform LDS byte base
    }

    auto stage_pair = [&](int buf, int kt, int i) {
        const u16* ag = A  + (size_t)bm * lda + kt * 64;
        const u16* bg = Bw + (size_t)bn * ldb + kt * 64;
        gload_lds16(ag + (size_t)srow[i] * lda + scol[i], lds + buf * 32768 + sdst[i]);
        gload_lds16(bg + (size_t)srow[i] * ldb + scol[i], lds + 65536 + buf * 32768 + sdst[i]);
    };

    f32x4 acc[8][4] = {};
    const int nt = K >> 6;

#pragma unroll
    for (int i = 0; i < 4; ++i) stage_pair(0, 0, i);

    for (int t = 0; t < nt; ++t) {
        const char* Ab = lds + (t & 1) * 32768;
        const char* Bb = lds + 65536 + (t & 1) * 32768;
        const bool nxt = (t + 1 < nt);
        const int nb = (t + 1) & 1;

        short8 af[4], bf[4];

        auto rdA = [&](int mh, int ks) {
#pragma unroll
            for (int mi = 0; mi < 4; ++mi) {
                const int row = wm * 128 + mh * 64 + mi * 16 + l15;
                af[mi] = *reinterpret_cast<const short8*>(
                    Ab + row * 128 + (((ks * 4 + kq) ^ (row & 7)) * 16));
            }
        };
        auto rdB = [&](int ks) {
#pragma unroll
            for (int ni = 0; ni < 4; ++ni) {
                const int row = wn * 64 + ni * 16 + l15;
                bf[ni] = *reinterpret_cast<const short8*>(
                    Bb + row * 128 + (((ks * 4 + kq) ^ (row & 7)) * 16));
            }
        };
        auto mfma16 = [&](int mh) {
            asm volatile("s_waitcnt lgkmcnt(0)" ::: "memory");
            __builtin_amdgcn_sched_barrier(0);
            __builtin_amdgcn_s_setprio(1);
#pragma unroll
            for (int mi = 0; mi < 4; ++mi)
#pragma unroll
                for (int ni = 0; ni < 4; ++ni)
                    acc[mh * 4 + mi][ni] = __builtin_amdgcn_mfma_f32_16x16x32_bf16(
                        af[mi], bf[ni], acc[mh * 4 + mi][ni], 0, 0, 0);
            __builtin_amdgcn_s_setprio(0);
            asm volatile("" ::: "memory");
            __builtin_amdgcn_s_barrier();
            asm volatile("" ::: "memory");
        };

        // ---- phase 0: publish buf t; counted vmcnt; quadrant (mh=0, ks=0)
        if (nxt) { stage_pair(nb, t + 1, 0); stage_pair(nb, t + 1, 1); }
        if (nxt) asm volatile("s_waitcnt vmcnt(4)" ::: "memory");
        else     asm volatile("s_waitcnt vmcnt(0)" ::: "memory");
        __builtin_amdgcn_sched_barrier(0);
        __builtin_amdgcn_s_barrier();
        asm volatile("" ::: "memory");
        rdB(0); rdA(0, 0);
        mfma16(0);

        // ---- phase 1: (mh=1, ks=0), issue remaining prefetch
        if (nxt) { stage_pair(nb, t + 1, 2); stage_pair(nb, t + 1, 3); }
        rdA(1, 0);
        mfma16(1);

        // ---- phase 2: (mh=0, ks=1)
        rdB(1); rdA(0, 1);
        mfma16(0);

        // ---- phase 3: (mh=1, ks=1)
        rdA(1, 1);
        mfma16(1);
    }

#pragma unroll
    for (int mg = 0; mg < 8; ++mg) {
#pragma unroll
        for (int ni = 0; ni < 4; ++ni) {
            const int col = bn + wn * 64 + ni * 16 + l15;
            const float bv = BIAS ? bias[col] : 0.f;
#pragma unroll
            for (int r = 0; r < 4; ++r) {
                const int row = bm + wm * 128 + mg * 16 + kq * 4 + r;
                float v = acc[mg][ni][r] + bv;
                u16* cp = C + (size_t)row * ldc + col;
                if (ACCUM) v += bf2f(*cp);
                *cp = f2bf(v);
            }
        }
    }
}

// ---------------------------------------------------------------------------
// 128x128 m97-structure GEMM (h12, up, proj). KSEL: runtime K per task.
// VT: up-GEMM variant — V columns (abscol>=2304, i.e. rel col>=1152) are
// ALSO written transposed into vt (fuses the old transpose_v kernel).
// When task<mintask, gate=0 -> v = old value (qkvb unchanged) but vt still
// produced (correct for any task).
// ---------------------------------------------------------------------------
template<bool TANH, bool ACCUM, bool BIAS, bool OUT_BF16, bool KSEL, bool VT>
__global__ __launch_bounds__(256)
void gemm_mfma(const u16* __restrict__ A, const u16* __restrict__ Bw,
               const float* __restrict__ bias, void* __restrict__ Cv,
               u16* __restrict__ vt,
               int K, int lda, int ldb, int ldc,
               const int* __restrict__ taskp, int mintask)
{
    float gate = 1.f;
    if (taskp != nullptr && *taskp < mintask) {
        if (!VT) return;
        gate = 0.f;
    }
    if (KSEL && *taskp < 5) K = 256;

    __shared__ u16 As[2][128 * 64];
    __shared__ u16 Bs[2][128 * 64];

    const int tid  = threadIdx.x;
    const int lane = tid & 63;
    const int wv   = tid >> 6;
    const int wr   = (wv >> 1) * 64;
    const int wc   = (wv & 1) * 64;
    const int bm   = blockIdx.x * 128;
    const int bn   = blockIdx.y * 128;

    f32x4 acc[4][4] = {};

    const int srow = tid >> 3;
    const int sslt = tid & 7;

    auto stage = [&](int buf, int k0) {
        const u16* ab = A  + (size_t)bm * lda + k0;
        const u16* bb = Bw + (size_t)bn * ldb + k0;
#pragma unroll
        for (int i = 0; i < 4; ++i) {
            const int row = i * 32 + srow;
            gload_lds16(ab + (size_t)row * lda + sslt * 8,
                        (char*)&As[buf][0] + (i * 256 + (tid & 192)) * 16);
        }
#pragma unroll
        for (int i = 0; i < 4; ++i) {
            const int row = i * 32 + srow;
            gload_lds16(bb + (size_t)row * ldb + sslt * 8,
                        (char*)&Bs[buf][0] + (i * 256 + (tid & 192)) * 16);
        }
    };

    stage(0, 0);
    const int nk = K >> 6;
    for (int kt = 0; kt < nk; ++kt) {
        __syncthreads();
        if (kt + 1 < nk) stage((kt + 1) & 1, (kt + 1) * 64);
        const u16* as = &As[kt & 1][0];
        const u16* bs = &Bs[kt & 1][0];
#pragma unroll
        for (int ks = 0; ks < 2; ++ks) {
            short8 af[4], bf[4];
#pragma unroll
            for (int mi = 0; mi < 4; ++mi) {
                const int row = wr + mi * 16 + (lane & 15);
                af[mi] = *reinterpret_cast<const short8*>(as + row * 64 + ks * 32 + (lane >> 4) * 8);
            }
#pragma unroll
            for (int ni = 0; ni < 4; ++ni) {
                const int row = wc + ni * 16 + (lane & 15);
                bf[ni] = *reinterpret_cast<const short8*>(bs + row * 64 + ks * 32 + (lane >> 4) * 8);
            }
#pragma unroll
            for (int mi = 0; mi < 4; ++mi)
#pragma unroll
                for (int ni = 0; ni < 4; ++ni)
                    acc[mi][ni] = __builtin_amdgcn_mfma_f32_16x16x32_bf16(
                        af[mi], bf[ni], acc[mi][ni], 0, 0, 0);
        }
    }

#pragma unroll
    for (int mi = 0; mi < 4; ++mi) {
#pragma unroll
        for (int ni = 0; ni < 4; ++ni) {
            const int col = bn + wc + ni * 16 + (lane & 15);
            const float bv = BIAS ? bias[col] : 0.f;
            ushort4 tv;
#pragma unroll
            for (int r = 0; r < 4; ++r) {
                const int row = bm + wr + mi * 16 + (lane >> 4) * 4 + r;
                float v = gate * (acc[mi][ni][r] + bv);
                if (TANH) v = tanhf(v);
                if (OUT_BF16) {
                    u16* cp = (u16*)Cv + (size_t)row * ldc + col;
                    if (ACCUM) v += bf2f(*cp);
                    const u16 bb = f2bf(v);
                    *cp = bb;
                    if (VT) (&tv.x)[r] = bb;
                } else {
                    float* cp = (float*)Cv + (size_t)row * ldc + col;
                    if (ACCUM) v += *cp;
                    *cp = v;
                }
            }
            if (VT && col >= 1152) {   // V region: abscol = col + 1152 >= 2304
                const int hh = (col - 1152) >> 7;
                const int d  = (col - 1152) & 127;
                const int row0 = bm + wr + mi * 16 + (lane >> 4) * 4;
                const int bb_  = row0 >> 10;
                const int tok  = row0 & 1023;
                *reinterpret_cast<ushort4*>(
                    vt + ((size_t)(bb_ * kHeads + hh) * 128 + d) * kN + tok) = tv;
            }
        }
    }
}

// ---------------------------------------------------------------------------
// MFMA flash attention, INTRA-BLOCK KV-SPLIT + T14 async-STAGE split:
// global loads for tile t+1 are issued into REGISTERS before computing
// tile t (HBM/L2 latency hides under QK/softmax/PV), then written to LDS
// after the post-compute barrier. LDS stays 32 KiB (5 blocks/CU preserved);
// +32 VGPR for the in-flight tile (target <=128 total).
// ---------------------------------------------------------------------------
__global__ __launch_bounds__(256)
void attn_mfma(const u16* __restrict__ qkv, const u16* __restrict__ vt,
               u16* __restrict__ out)
{
    __shared__ u16 Ks[2][32 * 128];   // [kvhalf][tok][d] swizzled, 8 KB each
    __shared__ u16 Vs[2][128 * 32];   // [kvhalf][d][tok] swizzled, 8 KB each

    const int bh = blockIdx.x, b = bh / kHeads, h = bh - b * kHeads;
    const int tid = threadIdx.x, lane = tid & 63, wv = tid >> 6;
    const int lo5 = lane & 31;
    const bool hihalf = (lane >= 32);
    const int hi = hihalf ? 1 : 0;
    const int qh = wv >> 1;                 // q half within the 64-row block
    const int kh = wv & 1;                  // kv half (tokens kh*512 ..)
    const int q0 = blockIdx.y * 64 + qh * 32;

    // Q frags (B-operand): q = lo5, d = f*16 + hi*8 + e (pre-scaled by kCexp)
    const u16* qp = qkv + (size_t)(b * kN + q0 + lo5) * kQS + h * 128;
    short8 qf[8];
#pragma unroll
    for (int f = 0; f < 8; ++f)
        qf[f] = *reinterpret_cast<const short8*>(qp + f * 16 + hi * 8);

    // staging offsets (pre-swizzled global source, linear LDS dst).
    int koff[2], voff[2];
#pragma unroll
    for (int j = 0; j < 2; ++j) {
        const int I = j * 256 + tid;        // 0..511
        const int tok = I >> 4, s = I & 15;
        koff[j] = tok * kQS + ((s ^ (tok & 7)) * 8);
        const int d = I >> 2, sv = I & 3;
        voff[j] = d * kN + ((sv ^ (d & 3)) * 8);
    }
    const u16* kbase = qkv + (size_t)b * kN * kQS + kDim + h * 128;
    const u16* vbase = vt + (size_t)bh * 128 * kN;

    // T14 register staging: 8 x 16B in flight (4 K + 4 V)
    uint4 kr0, kr1, kr2, kr3, vr0, vr1, vr2, vr3;
    auto ldregs = [&](int t) {
        const int kt0 = t * 32, kt1 = 512 + t * 32;
        kr0 = *reinterpret_cast<const uint4*>(kbase + (size_t)kt0 * kQS + koff[0]);
        kr1 = *reinterpret_cast<const uint4*>(kbase + (size_t)kt0 * kQS + koff[1]);
        kr2 = *reinterpret_cast<const uint4*>(kbase + (size_t)kt1 * kQS + koff[0]);
        kr3 = *reinterpret_cast<const uint4*>(kbase + (size_t)kt1 * kQS + koff[1]);
        vr0 = *reinterpret_cast<const uint4*>(vbase + kt0 + voff[0]);
        vr1 = *reinterpret_cast<const uint4*>(vbase + kt0 + voff[1]);
        vr2 = *reinterpret_cast<const uint4*>(vbase + kt1 + voff[0]);
        vr3 = *reinterpret_cast<const uint4*>(vbase + kt1 + voff[1]);
    };
    auto stlds = [&]() {
        *reinterpret_cast<uint4*>((char*)&Ks[0][0] + (0 * 256 + wv * 64 + lane) * 16) = kr0;
        *reinterpret_cast<uint4*>((char*)&Ks[0][0] + (1 * 256 + wv * 64 + lane) * 16) = kr1;
        *reinterpret_cast<uint4*>((char*)&Ks[1][0] + (0 * 256 + wv * 64 + lane) * 16) = kr2;
        *reinterpret_cast<uint4*>((char*)&Ks[1][0] + (1 * 256 + wv * 64 + lane) * 16) = kr3;
        *reinterpret_cast<uint4*>((char*)&Vs[0][0] + (0 * 256 + wv * 64 + lane) * 16) = vr0;
        *reinterpret_cast<uint4*>((char*)&Vs[0][0] + (1 * 256 + wv * 64 + lane) * 16) = vr1;
        *reinterpret_cast<uint4*>((char*)&Vs[1][0] + (0 * 256 + wv * 64 + lane) * 16) = vr2;
        *reinterpret_cast<uint4*>((char*)&Vs[1][0] + (1 * 256 + wv * 64 + lane) * 16) = vr3;
    };

    f32x16 o[4] = {};
    float l = 0.f;

    ldregs(0);
    stlds();
    __syncthreads();

    for (int t = 0; t < 16; ++t) {
        if (t + 1 < 16) ldregs(t + 1);   // in flight during compute of tile t

        const char* ks = (const char*)&Ks[kh][0];
        const char* vs = (const char*)&Vs[kh][0];

        // S^T = K Q^T : A = K rows (32 ktok), B = Q(log2 units). col(q)=lo5
        f32x16 s0 = {};
        __builtin_amdgcn_s_setprio(1);
#pragma unroll
        for (int f = 0; f < 8; ++f) {
            const short8 ka = *reinterpret_cast<const short8*>(
                ks + lo5 * 256 + (((f * 2 + hi) * 16) ^ ((lo5 & 7) << 4)));
            s0 = __builtin_amdgcn_mfma_f32_32x32x16_bf16(ka, qf[f], s0, 0, 0, 0);
        }
        __builtin_amdgcn_s_setprio(0);

        // fixed-zero-max softmax: p = exp2(s) directly
        float rsum = 0.f;
#pragma unroll
        for (int r = 0; r < 16; ++r) { s0[r] = exp2f(s0[r]); rsum += s0[r]; }
        rsum += __shfl_xor(rsum, 32);
        l += rsum;

        // P frags (B-operand, k = hi*8+e per 16-ktok chunk)
        short8 pf[2];
        pf[0] = build_pfrag(s0[0], s0[1], s0[2], s0[3], s0[4], s0[5], s0[6], s0[7], hihalf);
        pf[1] = build_pfrag(s0[8], s0[9], s0[10], s0[11], s0[12], s0[13], s0[14], s0[15], hihalf);

        // O^T += V^T P : A = V^T rows (d, 32-tok cols), B = P^T. col(q)=lo5
        __builtin_amdgcn_s_setprio(1);
#pragma unroll
        for (int dt = 0; dt < 4; ++dt) {
            const int drow = dt * 32 + lo5;
#pragma unroll
            for (int c = 0; c < 2; ++c) {
                const short8 va = *reinterpret_cast<const short8*>(
                    vs + drow * 64 + (((c * 2 + hi) * 16) ^ ((drow & 3) << 4)));
                o[dt] = __builtin_amdgcn_mfma_f32_32x32x16_bf16(va, pf[c], o[dt], 0, 0, 0);
            }
        }
        __builtin_amdgcn_s_setprio(0);

        __syncthreads();                 // all waves done reading tile t
        if (t + 1 < 16) stlds();         // publish tile t+1 (loads drained here)
        __syncthreads();
    }

    // ---- pair combine through dead LDS (waves kh=1 -> kh=0), then output.
    char* exch = (char*)&Ks[0][0];
    float* ls  = (float*)&Vs[0][0];
    if (kh == 1) {
#pragma unroll
        for (int dt = 0; dt < 4; ++dt) {
#pragma unroll
            for (int rg = 0; rg < 4; ++rg) {
                const int kb = (dt * 4 + rg) * 8;     // 8-byte chunk index
                ushort4 w;
                w.x = f2bf(o[dt][rg * 4 + 0]);
                w.y = f2bf(o[dt][rg * 4 + 1]);
                w.z = f2bf(o[dt][rg * 4 + 2]);
                w.w = f2bf(o[dt][rg * 4 + 3]);
                *reinterpret_cast<ushort4*>(
                    exch + qh * 8192 + lane * 128 + (kb ^ ((lane & 7) << 3))) = w;
            }
        }
        if (!hihalf) ls[qh * 32 + lo5] = l;
    }
    __syncthreads();
    if (kh == 0) {
        const float inv = 1.f / (l + ls[qh * 32 + lo5]);
        u16* op = out + (size_t)(b * kN + q0 + lo5) * kDim + h * 128;
#pragma unroll
        for (int dt = 0; dt < 4; ++dt) {
#pragma unroll
            for (int rg = 0; rg < 4; ++rg) {
                const int kb = (dt * 4 + rg) * 8;
                const ushort4 pv = *reinterpret_cast<const ushort4*>(
                    exch + qh * 8192 + lane * 128 + (kb ^ ((lane & 7) << 3)));
                const int d0 = dt * 32 + rg * 8 + hi * 4;
                ushort4 v;
                v.x = f2bf((o[dt][rg * 4 + 0] + bf2f(pv.x)) * inv);
                v.y = f2bf((o[dt][rg * 4 + 1] + bf2f(pv.y)) * inv);
                v.z = f2bf((o[dt][rg * 4 + 2] + bf2f(pv.z)) * inv);
                v.w = f2bf((o[dt][rg * 4 + 3] + bf2f(pv.w)) * inv);
                *reinterpret_cast<ushort4*>(op + d0) = v;
            }
        }
    }
}

}  // namespace

extern "C" void kernel_launch(void* const* d_in, const int* in_sizes, int n_in,
                              void* d_out, int out_size, void* d_ws, size_t ws_size,
                              hipStream_t stream)
{
    const float* x       = (const float*)d_in[0];
    const float* Wqkv    = (const float*)d_in[1];
    const float* Wproj   = (const float*)d_in[2];
    const float* bproj   = (const float*)d_in[3];
    const float* down_w  = (const float*)d_in[4];
    const float* down_b  = (const float*)d_in[5];
    const float* up_w    = (const float*)d_in[6];
    const float* up_b    = (const float*)d_in[7];
    const float* pdown_w = (const float*)d_in[8];
    const float* pdown_b = (const float*)d_in[9];
    const float* pup_w   = (const float*)d_in[10];
    const float* pup_b   = (const float*)d_in[11];
    const int*   task    = (const int*)d_in[12];

    // ws layout (u16 elements). xb and vt share a region (x dead before vt written:
    // vt is written by the up-GEMM epilogue, which runs after qkv/h12 consumed xb).
    u16* xb_vt  = (u16*)d_ws;                          //  9,437,184
    u16* wqkvb  = xb_vt  + (size_t)kM * kDim;          //  [3456+128pad][1152]
    u16* wprjb  = wqkvb  + (size_t)kQS * kDim;         //  1,327,104
    u16* wdownb = wprjb  + (size_t)kDim * kDim;        //  [512][1152]
    u16* wupb   = wdownb + (size_t)512 * kDim;         //  [2304][512]
    u16* h12    = wupb   + (size_t)2304 * 512;         //  [8192][512]
    u16* qkvb   = h12    + (size_t)kM * 512;           //  [8192][3584] padded
    u16* aob    = qkvb   + (size_t)kM * kQS;           //  [8192][1152]
    float* bd   = (float*)(aob + (size_t)kM * kDim);   //  512 f32
    float* bu   = bd + 512;                            //  2304 f32
    float* out  = (float*)d_out;
    u16* xb = xb_vt;
    u16* vt = xb_vt;

    prep_all<<<kPrepGrid, 256, 0, stream>>>(
        x, Wqkv, Wproj, down_w, pdown_w, up_w, pup_w,
        down_b, pdown_b, up_b, pup_b, task,
        xb, wqkvb, wprjb, wdownb, wupb, bd, bu);

    hipFuncSetAttribute(reinterpret_cast<const void*>(&gemm8p<false, false>),
                        hipFuncAttributeMaxDynamicSharedMemorySize, 131072);

    // h12 = tanh(x @ [down_w;pdown_w]^T + bd)
    gemm_mfma<true, false, true, true, false, false><<<dim3(kM / 128, 4), 256, 0, stream>>>(
        xb, wdownb, bd, h12, nullptr, kDim, kDim, kDim, 512, nullptr, 0);
    // qkv = x @ Wqkv^T   (256^2 8-phase; N padded to 3584; Q pre-scaled)
    gemm8p<false, false><<<dim3(kM / 256, kQS / 256), 512, 131072, stream>>>(
        xb, wqkvb, nullptr, qkvb, kDim, kDim, kDim, kQS);
    // qkv[:,1152:3456] += h12 @ wupb^T + bu, AND write V columns transposed
    // into vt (fused transpose_v). gate=0 path keeps qkvb when task<4.
    gemm_mfma<false, true, true, true, true, true><<<dim3(kM / 128, 18), 256, 0, stream>>>(
        h12, wupb, bu, qkvb + kDim, vt, 512, 512, 512, kQS, task, 4);

    // attention (intra-block KV-split + T14 reg-staging, 1152 blocks, 32 KiB LDS)
    attn_mfma<<<dim3(kB * kHeads, kN / 64), 256, 0, stream>>>(qkvb, vt, aob);

    // out = attn_out @ Wproj^T + bproj  (fp32)
    gemm_mfma<false, false, true, false, false, false><<<dim3(kM / 128, 9), 256, 0, stream>>>(
        aob, wprjb, bproj, out, nullptr, kDim, kDim, kDim, kDim, nullptr, 0);

    // second output: down_w passthrough
    hipMemcpyAsync(out + (size_t)kM * kDim, down_w,
                   (size_t)kMid * kDim * sizeof(float),
                   hipMemcpyDeviceToDevice, stream);
}

// Round 16
// 327.603 us; speedup vs baseline: 1.0313x; 1.0313x over previous
//
#include <hip/hip_runtime.h>
#include <math.h>

namespace {

typedef unsigned short u16;
typedef __attribute__((ext_vector_type(8))) short short8;   // 8 bf16 = 4 VGPRs
typedef __attribute__((ext_vector_type(4))) float f32x4;
typedef __attribute__((ext_vector_type(16))) float f32x16;

constexpr int kDim   = 1152;
constexpr int kHeads = 9;
constexpr int kMid   = 256;
constexpr int kB     = 8;
constexpr int kN     = 1024;
constexpr int kM     = kB * kN;                 // 8192 tokens
constexpr int kQS    = 3584;                    // padded qkv row stride (14*256)
constexpr float kCexp  = 0.12753837360881433f;  // 128^-0.5 * log2(e), folded into Wq

__device__ __forceinline__ u16 f2bf(float f) {
    unsigned u = __builtin_bit_cast(unsigned, f);
    return (u16)((u + 0x7FFFu + ((u >> 16) & 1u)) >> 16);
}
__device__ __forceinline__ float bf2f(u16 h) {
    unsigned u = ((unsigned)h) << 16;
    return __builtin_bit_cast(float, u);
}

// async global->LDS, 16B/lane. dst wave-uniform; lane i lands at dst + i*16.
__device__ __forceinline__ void gload_lds16(const void* g, void* l) {
    __builtin_amdgcn_global_load_lds(
        (const __attribute__((address_space(1))) unsigned int*)g,
        (__attribute__((address_space(3))) unsigned int*)l,
        16, 0, 0);
}

__device__ __forceinline__ unsigned cvtpk(float a, float b) {
    unsigned r;
    asm volatile("v_cvt_pk_bf16_f32 %0, %1, %2" : "=v"(r) : "v"(a), "v"(b));
    return r;  // lo16 = bf16(a), hi16 = bf16(b)
}

// exchange: x' = [x_lo, y_lo(partner)], y' = [x_hi(partner), y_hi]
__device__ __forceinline__ void halfswap(unsigned& x, unsigned& y, bool hihalf) {
    const unsigned xs = (unsigned)__shfl_xor((int)x, 32);
    const unsigned ys = (unsigned)__shfl_xor((int)y, 32);
    const unsigned nx = hihalf ? ys : x;
    const unsigned ny = hihalf ? y : xs;
    x = nx; y = ny;
}

__device__ __forceinline__ short8 build_pfrag(float p0, float p1, float p2, float p3,
                                              float p4, float p5, float p6, float p7,
                                              bool hihalf) {
    unsigned x1 = cvtpk(p0, p1), y1 = cvtpk(p4, p5);
    unsigned x2 = cvtpk(p2, p3), y2 = cvtpk(p6, p7);
    halfswap(x1, y1, hihalf);
    halfswap(x2, y2, hihalf);
    union { unsigned u[4]; short8 s; } pk;
    pk.u[0] = x1; pk.u[1] = x2; pk.u[2] = y1; pk.u[3] = y2;
    return pk.s;
}

// ---------------------------------------------------------------------------
// One fused prep kernel. Wqkv q-rows scaled by kCexp in f32 before bf16
// conversion (softmax scale folded into Q — exact linearity).
// ---------------------------------------------------------------------------
constexpr int R0 = 2359296;            // x            [8192*1152/4]
constexpr int R1 = R0 + 995328;        // Wqkv         [3456*1152/4]
constexpr int R2 = R1 + 331776;        // Wproj        [1152*1152/4]
constexpr int R3 = R2 + 73728;         // down_w       [256*1152/4]
constexpr int R4 = R3 + 73728;         // pdown_w
constexpr int R5 = R4 + 147456;        // up_w         [2304*256/4] strided
constexpr int R6 = R5 + 147456;        // pup_w        strided
constexpr int R7 = R6 + 512;           // bd scalars
constexpr int R8 = R7 + 2304;          // bu scalars
constexpr int kQPart = 331776;         // Wqkv q-part float4 count (1152*1152/4)
constexpr int kPrepGrid = R8 / 256;    // 16139 exactly

__global__ __launch_bounds__(256)
void prep_all(const float* __restrict__ x, const float* __restrict__ Wqkv,
              const float* __restrict__ Wproj,
              const float* __restrict__ down_w, const float* __restrict__ pdown_w,
              const float* __restrict__ up_w, const float* __restrict__ pup_w,
              const float* __restrict__ down_b, const float* __restrict__ pdown_b,
              const float* __restrict__ up_b, const float* __restrict__ pup_b,
              const int* __restrict__ task,
              u16* __restrict__ xb, u16* __restrict__ wqkvb, u16* __restrict__ wprjb,
              u16* __restrict__ wdownb, u16* __restrict__ wupb,
              float* __restrict__ bd, float* __restrict__ bu)
{
    const int i = blockIdx.x * blockDim.x + threadIdx.x;
    auto cvt4s = [](const float* s, int j, float sc) {
        const float4 v = reinterpret_cast<const float4*>(s)[j];
        ushort4 o;
        o.x = f2bf(v.x * sc); o.y = f2bf(v.y * sc);
        o.z = f2bf(v.z * sc); o.w = f2bf(v.w * sc);
        return o;
    };
    if (i < R0) {
        reinterpret_cast<ushort4*>(xb)[i] = cvt4s(x, i, 1.f);
    } else if (i < R1) {
        const int j = i - R0;
        const float sc = (j < kQPart) ? kCexp : 1.f;   // fold softmax scale into Wq
        reinterpret_cast<ushort4*>(wqkvb)[j] = cvt4s(Wqkv, j, sc);
    } else if (i < R2) {
        reinterpret_cast<ushort4*>(wprjb)[i - R1] = cvt4s(Wproj, i - R1, 1.f);
    } else if (i < R3) {
        reinterpret_cast<ushort4*>(wdownb)[i - R2] = cvt4s(down_w, i - R2, 1.f);
    } else if (i < R4) {
        reinterpret_cast<ushort4*>(wdownb)[73728 + (i - R3)] = cvt4s(pdown_w, i - R3, 1.f);
    } else if (i < R5) {
        const int j = i - R4, r = j >> 6, c = j & 63;
        reinterpret_cast<ushort4*>(wupb)[r * 128 + c] = cvt4s(up_w, j, 1.f);
    } else if (i < R6) {
        const int j = i - R5, r = j >> 6, c = j & 63;
        reinterpret_cast<ushort4*>(wupb)[r * 128 + 64 + c] = cvt4s(pup_w, j, 1.f);
    } else if (i < R7) {
        const int j = i - R6;
        bd[j] = (j < 256) ? down_b[j] : pdown_b[j - 256];
    } else {
        const int j = i - R7;
        bu[j] = up_b[j] + ((*task >= 5) ? pup_b[j] : 0.f);
    }
}

// ---------------------------------------------------------------------------
// 256x256 tile GEMM, 8-phase template (T3+T4). qkv only (r13 configuration).
// ---------------------------------------------------------------------------
template<bool ACCUM, bool BIAS>
__global__ __launch_bounds__(512, 2)
void gemm8p(const u16* __restrict__ A, const u16* __restrict__ Bw,
            const float* __restrict__ bias, u16* __restrict__ C,
            int K, int lda, int ldb, int ldc)
{
    extern __shared__ char lds[];   // [A0 32K][A1 32K][B0 32K][B1 32K]

    const int tid  = threadIdx.x;
    const int lane = tid & 63;
    const int wid  = tid >> 6;
    const int wm   = wid >> 2;             // 0..1 : 128-row half
    const int wn   = wid & 3;              // 0..3 : 64-col quarter
    const int bm   = blockIdx.x * 256;
    const int bn   = blockIdx.y * 256;
    const int l15  = lane & 15;
    const int kq   = lane >> 4;            // 0..3

    int srow[4], scol[4], sdst[4];
#pragma unroll
    for (int i = 0; i < 4; ++i) {
        const int id = i * 512 + tid;
        srow[i] = id >> 3;
        const int s = id & 7;
        scol[i] = (s ^ (srow[i] & 7)) * 8;          // pre-swizzled source col (elems)
        sdst[i] = (i * 512 + wid * 64) * 16;        // wave-uniform LDS byte base
    }

    auto stage_pair = [&](int buf, int kt, int i) {
        const u16* ag = A  + (size_t)bm * lda + kt * 64;
        const u16* bg = Bw + (size_t)bn * ldb + kt * 64;
        gload_lds16(ag + (size_t)srow[i] * lda + scol[i], lds + buf * 32768 + sdst[i]);
        gload_lds16(bg + (size_t)srow[i] * ldb + scol[i], lds + 65536 + buf * 32768 + sdst[i]);
    };

    f32x4 acc[8][4] = {};
    const int nt = K >> 6;

#pragma unroll
    for (int i = 0; i < 4; ++i) stage_pair(0, 0, i);

    for (int t = 0; t < nt; ++t) {
        const char* Ab = lds + (t & 1) * 32768;
        const char* Bb = lds + 65536 + (t & 1) * 32768;
        const bool nxt = (t + 1 < nt);
        const int nb = (t + 1) & 1;

        short8 af[4], bf[4];

        auto rdA = [&](int mh, int ks) {
#pragma unroll
            for (int mi = 0; mi < 4; ++mi) {
                const int row = wm * 128 + mh * 64 + mi * 16 + l15;
                af[mi] = *reinterpret_cast<const short8*>(
                    Ab + row * 128 + (((ks * 4 + kq) ^ (row & 7)) * 16));
            }
        };
        auto rdB = [&](int ks) {
#pragma unroll
            for (int ni = 0; ni < 4; ++ni) {
                const int row = wn * 64 + ni * 16 + l15;
                bf[ni] = *reinterpret_cast<const short8*>(
                    Bb + row * 128 + (((ks * 4 + kq) ^ (row & 7)) * 16));
            }
        };
        auto mfma16 = [&](int mh) {
            asm volatile("s_waitcnt lgkmcnt(0)" ::: "memory");
            __builtin_amdgcn_sched_barrier(0);
            __builtin_amdgcn_s_setprio(1);
#pragma unroll
            for (int mi = 0; mi < 4; ++mi)
#pragma unroll
                for (int ni = 0; ni < 4; ++ni)
                    acc[mh * 4 + mi][ni] = __builtin_amdgcn_mfma_f32_16x16x32_bf16(
                        af[mi], bf[ni], acc[mh * 4 + mi][ni], 0, 0, 0);
            __builtin_amdgcn_s_setprio(0);
            asm volatile("" ::: "memory");
            __builtin_amdgcn_s_barrier();
            asm volatile("" ::: "memory");
        };

        // ---- phase 0: publish buf t; counted vmcnt; quadrant (mh=0, ks=0)
        if (nxt) { stage_pair(nb, t + 1, 0); stage_pair(nb, t + 1, 1); }
        if (nxt) asm volatile("s_waitcnt vmcnt(4)" ::: "memory");
        else     asm volatile("s_waitcnt vmcnt(0)" ::: "memory");
        __builtin_amdgcn_sched_barrier(0);
        __builtin_amdgcn_s_barrier();
        asm volatile("" ::: "memory");
        rdB(0); rdA(0, 0);
        mfma16(0);

        // ---- phase 1: (mh=1, ks=0), issue remaining prefetch
        if (nxt) { stage_pair(nb, t + 1, 2); stage_pair(nb, t + 1, 3); }
        rdA(1, 0);
        mfma16(1);

        // ---- phase 2: (mh=0, ks=1)
        rdB(1); rdA(0, 1);
        mfma16(0);

        // ---- phase 3: (mh=1, ks=1)
        rdA(1, 1);
        mfma16(1);
    }

#pragma unroll
    for (int mg = 0; mg < 8; ++mg) {
#pragma unroll
        for (int ni = 0; ni < 4; ++ni) {
            const int col = bn + wn * 64 + ni * 16 + l15;
            const float bv = BIAS ? bias[col] : 0.f;
#pragma unroll
            for (int r = 0; r < 4; ++r) {
                const int row = bm + wm * 128 + mg * 16 + kq * 4 + r;
                float v = acc[mg][ni][r] + bv;
                u16* cp = C + (size_t)row * ldc + col;
                if (ACCUM) v += bf2f(*cp);
                *cp = f2bf(v);
            }
        }
    }
}

// ---------------------------------------------------------------------------
// 128x128 m97-structure GEMM (h12, up, proj). KSEL: runtime K per task.
// VT: up-GEMM variant — V columns also written transposed into vt (fused
// transpose_v; r15-proven). gate=0 keeps qkvb when task<4, vt always valid.
// ---------------------------------------------------------------------------
template<bool TANH, bool ACCUM, bool BIAS, bool OUT_BF16, bool KSEL, bool VT>
__global__ __launch_bounds__(256)
void gemm_mfma(const u16* __restrict__ A, const u16* __restrict__ Bw,
               const float* __restrict__ bias, void* __restrict__ Cv,
               u16* __restrict__ vt,
               int K, int lda, int ldb, int ldc,
               const int* __restrict__ taskp, int mintask)
{
    float gate = 1.f;
    if (taskp != nullptr && *taskp < mintask) {
        if (!VT) return;
        gate = 0.f;
    }
    if (KSEL && *taskp < 5) K = 256;

    __shared__ u16 As[2][128 * 64];
    __shared__ u16 Bs[2][128 * 64];

    const int tid  = threadIdx.x;
    const int lane = tid & 63;
    const int wv   = tid >> 6;
    const int wr   = (wv >> 1) * 64;
    const int wc   = (wv & 1) * 64;
    const int bm   = blockIdx.x * 128;
    const int bn   = blockIdx.y * 128;

    f32x4 acc[4][4] = {};

    const int srow = tid >> 3;
    const int sslt = tid & 7;

    auto stage = [&](int buf, int k0) {
        const u16* ab = A  + (size_t)bm * lda + k0;
        const u16* bb = Bw + (size_t)bn * ldb + k0;
#pragma unroll
        for (int i = 0; i < 4; ++i) {
            const int row = i * 32 + srow;
            gload_lds16(ab + (size_t)row * lda + sslt * 8,
                        (char*)&As[buf][0] + (i * 256 + (tid & 192)) * 16);
        }
#pragma unroll
        for (int i = 0; i < 4; ++i) {
            const int row = i * 32 + srow;
            gload_lds16(bb + (size_t)row * ldb + sslt * 8,
                        (char*)&Bs[buf][0] + (i * 256 + (tid & 192)) * 16);
        }
    };

    stage(0, 0);
    const int nk = K >> 6;
    for (int kt = 0; kt < nk; ++kt) {
        __syncthreads();
        if (kt + 1 < nk) stage((kt + 1) & 1, (kt + 1) * 64);
        const u16* as = &As[kt & 1][0];
        const u16* bs = &Bs[kt & 1][0];
#pragma unroll
        for (int ks = 0; ks < 2; ++ks) {
            short8 af[4], bf[4];
#pragma unroll
            for (int mi = 0; mi < 4; ++mi) {
                const int row = wr + mi * 16 + (lane & 15);
                af[mi] = *reinterpret_cast<const short8*>(as + row * 64 + ks * 32 + (lane >> 4) * 8);
            }
#pragma unroll
            for (int ni = 0; ni < 4; ++ni) {
                const int row = wc + ni * 16 + (lane & 15);
                bf[ni] = *reinterpret_cast<const short8*>(bs + row * 64 + ks * 32 + (lane >> 4) * 8);
            }
#pragma unroll
            for (int mi = 0; mi < 4; ++mi)
#pragma unroll
                for (int ni = 0; ni < 4; ++ni)
                    acc[mi][ni] = __builtin_amdgcn_mfma_f32_16x16x32_bf16(
                        af[mi], bf[ni], acc[mi][ni], 0, 0, 0);
        }
    }

#pragma unroll
    for (int mi = 0; mi < 4; ++mi) {
#pragma unroll
        for (int ni = 0; ni < 4; ++ni) {
            const int col = bn + wc + ni * 16 + (lane & 15);
            const float bv = BIAS ? bias[col] : 0.f;
            ushort4 tv;
#pragma unroll
            for (int r = 0; r < 4; ++r) {
                const int row = bm + wr + mi * 16 + (lane >> 4) * 4 + r;
                float v = gate * (acc[mi][ni][r] + bv);
                if (TANH) v = tanhf(v);
                if (OUT_BF16) {
                    u16* cp = (u16*)Cv + (size_t)row * ldc + col;
                    if (ACCUM) v += bf2f(*cp);
                    const u16 bb = f2bf(v);
                    *cp = bb;
                    if (VT) (&tv.x)[r] = bb;
                } else {
                    float* cp = (float*)Cv + (size_t)row * ldc + col;
                    if (ACCUM) v += *cp;
                    *cp = v;
                }
            }
            if (VT && col >= 1152) {   // V region: abscol = col + 1152 >= 2304
                const int hh = (col - 1152) >> 7;
                const int d  = (col - 1152) & 127;
                const int row0 = bm + wr + mi * 16 + (lane >> 4) * 4;
                const int bb_  = row0 >> 10;
                const int tok  = row0 & 1023;
                *reinterpret_cast<ushort4*>(
                    vt + ((size_t)(bb_ * kHeads + hh) * 128 + d) * kN + tok) = tv;
            }
        }
    }
}

// ---------------------------------------------------------------------------
// MFMA flash attention, INTRA-BLOCK KV-SPLIT (r13 configuration — measured
// 81 us @ 21.6% occupancy, VGPR 84). global_load_lds staging restored.
// ---------------------------------------------------------------------------
__global__ __launch_bounds__(256)
void attn_mfma(const u16* __restrict__ qkv, const u16* __restrict__ vt,
               u16* __restrict__ out)
{
    __shared__ u16 Ks[2][32 * 128];   // [kvhalf][tok][d] swizzled, 8 KB each
    __shared__ u16 Vs[2][128 * 32];   // [kvhalf][d][tok] swizzled, 8 KB each

    const int bh = blockIdx.x, b = bh / kHeads, h = bh - b * kHeads;
    const int tid = threadIdx.x, lane = tid & 63, wv = tid >> 6;
    const int lo5 = lane & 31;
    const bool hihalf = (lane >= 32);
    const int hi = hihalf ? 1 : 0;
    const int qh = wv >> 1;                 // q half within the 64-row block
    const int kh = wv & 1;                  // kv half (tokens kh*512 ..)
    const int q0 = blockIdx.y * 64 + qh * 32;

    // Q frags (B-operand): q = lo5, d = f*16 + hi*8 + e (pre-scaled by kCexp)
    const u16* qp = qkv + (size_t)(b * kN + q0 + lo5) * kQS + h * 128;
    short8 qf[8];
#pragma unroll
    for (int f = 0; f < 8; ++f)
        qf[f] = *reinterpret_cast<const short8*>(qp + f * 16 + hi * 8);

    // staging offsets (pre-swizzled global source, linear LDS dst).
    int koff[2], voff[2];
#pragma unroll
    for (int j = 0; j < 2; ++j) {
        const int I = j * 256 + tid;        // 0..511
        const int tok = I >> 4, s = I & 15;
        koff[j] = tok * kQS + ((s ^ (tok & 7)) * 8);
        const int d = I >> 2, sv = I & 3;
        voff[j] = d * kN + ((sv ^ (d & 3)) * 8);
    }
    const u16* kbase = qkv + (size_t)b * kN * kQS + kDim + h * 128;
    const u16* vbase = vt + (size_t)bh * 128 * kN;

    f32x16 o[4] = {};
    float l = 0.f;

    for (int t = 0; t < 16; ++t) {
        __syncthreads();   // prev iteration's readers done
#pragma unroll
        for (int hh = 0; hh < 2; ++hh) {
            const int kt = hh * 512 + t * 32;
#pragma unroll
            for (int j = 0; j < 2; ++j) {
                gload_lds16(kbase + (size_t)kt * kQS + koff[j],
                            (char*)&Ks[hh][0] + (j * 256 + wv * 64) * 16);
                gload_lds16(vbase + kt + voff[j],
                            (char*)&Vs[hh][0] + (j * 256 + wv * 64) * 16);
            }
        }
        __syncthreads();   // vmcnt(0) drained by compiler before barrier

        const char* ks = (const char*)&Ks[kh][0];
        const char* vs = (const char*)&Vs[kh][0];

        // S^T = K Q^T : A = K rows (32 ktok), B = Q(log2 units). col(q)=lo5
        f32x16 s0 = {};
        __builtin_amdgcn_s_setprio(1);
#pragma unroll
        for (int f = 0; f < 8; ++f) {
            const short8 ka = *reinterpret_cast<const short8*>(
                ks + lo5 * 256 + (((f * 2 + hi) * 16) ^ ((lo5 & 7) << 4)));
            s0 = __builtin_amdgcn_mfma_f32_32x32x16_bf16(ka, qf[f], s0, 0, 0, 0);
        }
        __builtin_amdgcn_s_setprio(0);

        // fixed-zero-max softmax: p = exp2(s) directly
        float rsum = 0.f;
#pragma unroll
        for (int r = 0; r < 16; ++r) { s0[r] = exp2f(s0[r]); rsum += s0[r]; }
        rsum += __shfl_xor(rsum, 32);
        l += rsum;

        // P frags (B-operand, k = hi*8+e per 16-ktok chunk)
        short8 pf[2];
        pf[0] = build_pfrag(s0[0], s0[1], s0[2], s0[3], s0[4], s0[5], s0[6], s0[7], hihalf);
        pf[1] = build_pfrag(s0[8], s0[9], s0[10], s0[11], s0[12], s0[13], s0[14], s0[15], hihalf);

        // O^T += V^T P : A = V^T rows (d, 32-tok cols), B = P^T. col(q)=lo5
        __builtin_amdgcn_s_setprio(1);
#pragma unroll
        for (int dt = 0; dt < 4; ++dt) {
            const int drow = dt * 32 + lo5;
#pragma unroll
            for (int c = 0; c < 2; ++c) {
                const short8 va = *reinterpret_cast<const short8*>(
                    vs + drow * 64 + (((c * 2 + hi) * 16) ^ ((drow & 3) << 4)));
                o[dt] = __builtin_amdgcn_mfma_f32_32x32x16_bf16(va, pf[c], o[dt], 0, 0, 0);
            }
        }
        __builtin_amdgcn_s_setprio(0);
    }

    // ---- pair combine through dead LDS (waves kh=1 -> kh=0), then output.
    __syncthreads();   // all waves done reading Ks/Vs
    char* exch = (char*)&Ks[0][0];
    float* ls  = (float*)&Vs[0][0];
    if (kh == 1) {
#pragma unroll
        for (int dt = 0; dt < 4; ++dt) {
#pragma unroll
            for (int rg = 0; rg < 4; ++rg) {
                const int kb = (dt * 4 + rg) * 8;     // 8-byte chunk index
                ushort4 w;
                w.x = f2bf(o[dt][rg * 4 + 0]);
                w.y = f2bf(o[dt][rg * 4 + 1]);
                w.z = f2bf(o[dt][rg * 4 + 2]);
                w.w = f2bf(o[dt][rg * 4 + 3]);
                *reinterpret_cast<ushort4*>(
                    exch + qh * 8192 + lane * 128 + (kb ^ ((lane & 7) << 3))) = w;
            }
        }
        if (!hihalf) ls[qh * 32 + lo5] = l;
    }
    __syncthreads();
    if (kh == 0) {
        const float inv = 1.f / (l + ls[qh * 32 + lo5]);
        u16* op = out + (size_t)(b * kN + q0 + lo5) * kDim + h * 128;
#pragma unroll
        for (int dt = 0; dt < 4; ++dt) {
#pragma unroll
            for (int rg = 0; rg < 4; ++rg) {
                const int kb = (dt * 4 + rg) * 8;
                const ushort4 pv = *reinterpret_cast<const ushort4*>(
                    exch + qh * 8192 + lane * 128 + (kb ^ ((lane & 7) << 3)));
                const int d0 = dt * 32 + rg * 8 + hi * 4;
                ushort4 v;
                v.x = f2bf((o[dt][rg * 4 + 0] + bf2f(pv.x)) * inv);
                v.y = f2bf((o[dt][rg * 4 + 1] + bf2f(pv.y)) * inv);
                v.z = f2bf((o[dt][rg * 4 + 2] + bf2f(pv.z)) * inv);
                v.w = f2bf((o[dt][rg * 4 + 3] + bf2f(pv.w)) * inv);
                *reinterpret_cast<ushort4*>(op + d0) = v;
            }
        }
    }
}

}  // namespace

extern "C" void kernel_launch(void* const* d_in, const int* in_sizes, int n_in,
                              void* d_out, int out_size, void* d_ws, size_t ws_size,
                              hipStream_t stream)
{
    const float* x       = (const float*)d_in[0];
    const float* Wqkv    = (const float*)d_in[1];
    const float* Wproj   = (const float*)d_in[2];
    const float* bproj   = (const float*)d_in[3];
    const float* down_w  = (const float*)d_in[4];
    const float* down_b  = (const float*)d_in[5];
    const float* up_w    = (const float*)d_in[6];
    const float* up_b    = (const float*)d_in[7];
    const float* pdown_w = (const float*)d_in[8];
    const float* pdown_b = (const float*)d_in[9];
    const float* pup_w   = (const float*)d_in[10];
    const float* pup_b   = (const float*)d_in[11];
    const int*   task    = (const int*)d_in[12];

    // ws layout (u16 elements). xb and vt share a region (x dead before vt
    // written: vt is produced by the up-GEMM epilogue, after qkv/h12 read xb).
    u16* xb_vt  = (u16*)d_ws;                          //  9,437,184
    u16* wqkvb  = xb_vt  + (size_t)kM * kDim;          //  [3456+128pad][1152]
    u16* wprjb  = wqkvb  + (size_t)kQS * kDim;         //  1,327,104
    u16* wdownb = wprjb  + (size_t)kDim * kDim;        //  [512][1152]
    u16* wupb   = wdownb + (size_t)512 * kDim;         //  [2304][512]
    u16* h12    = wupb   + (size_t)2304 * 512;         //  [8192][512]
    u16* qkvb   = h12    + (size_t)kM * 512;           //  [8192][3584] padded
    u16* aob    = qkvb   + (size_t)kM * kQS;           //  [8192][1152]
    float* bd   = (float*)(aob + (size_t)kM * kDim);   //  512 f32
    float* bu   = bd + 512;                            //  2304 f32
    float* out  = (float*)d_out;
    u16* xb = xb_vt;
    u16* vt = xb_vt;

    prep_all<<<kPrepGrid, 256, 0, stream>>>(
        x, Wqkv, Wproj, down_w, pdown_w, up_w, pup_w,
        down_b, pdown_b, up_b, pup_b, task,
        xb, wqkvb, wprjb, wdownb, wupb, bd, bu);

    hipFuncSetAttribute(reinterpret_cast<const void*>(&gemm8p<false, false>),
                        hipFuncAttributeMaxDynamicSharedMemorySize, 131072);

    // h12 = tanh(x @ [down_w;pdown_w]^T + bd)
    gemm_mfma<true, false, true, true, false, false><<<dim3(kM / 128, 4), 256, 0, stream>>>(
        xb, wdownb, bd, h12, nullptr, kDim, kDim, kDim, 512, nullptr, 0);
    // qkv = x @ Wqkv^T   (256^2 8-phase; N padded to 3584; Q pre-scaled)
    gemm8p<false, false><<<dim3(kM / 256, kQS / 256), 512, 131072, stream>>>(
        xb, wqkvb, nullptr, qkvb, kDim, kDim, kDim, kQS);
    // qkv[:,1152:3456] += h12 @ wupb^T + bu, AND write V columns transposed
    // into vt (fused transpose_v). gate=0 path keeps qkvb when task<4.
    gemm_mfma<false, true, true, true, true, true><<<dim3(kM / 128, 18), 256, 0, stream>>>(
        h12, wupb, bu, qkvb + kDim, vt, 512, 512, 512, kQS, task, 4);

    // attention (intra-block KV-split, gload_lds staging, 1152 blocks, 32 KiB LDS)
    attn_mfma<<<dim3(kB * kHeads, kN / 64), 256, 0, stream>>>(qkvb, vt, aob);

    // out = attn_out @ Wproj^T + bproj  (fp32)
    gemm_mfma<false, false, true, false, false, false><<<dim3(kM / 128, 9), 256, 0, stream>>>(
        aob, wprjb, bproj, out, nullptr, kDim, kDim, kDim, kDim, nullptr, 0);

    // second output: down_w passthrough
    hipMemcpyAsync(out + (size_t)kM * kDim, down_w,
                   (size_t)kMid * kDim * sizeof(float),
                   hipMemcpyDeviceToDevice, stream);
}

// Round 17
// 280.599 us; speedup vs baseline: 1.2041x; 1.1675x over previous
//
#include <hip/hip_runtime.h>
#include <math.h>

namespace {

typedef unsigned short u16;
typedef __attribute__((ext_vector_type(8))) short short8;   // 8 bf16 = 4 VGPRs
typedef __attribute__((ext_vector_type(4))) float f32x4;
typedef __attribute__((ext_vector_type(16))) float f32x16;

constexpr int kDim   = 1152;
constexpr int kHeads = 9;
constexpr int kMid   = 256;
constexpr int kB     = 8;
constexpr int kN     = 1024;
constexpr int kM     = kB * kN;                 // 8192 tokens
constexpr int kQS    = 3584;                    // padded qkv row stride (14*256)
constexpr int kKC    = 1664;                    // concatenated K (1152 + 512)
constexpr float kCexp  = 0.12753837360881433f;  // 128^-0.5 * log2(e), folded into Wq

__device__ __forceinline__ u16 f2bf(float f) {
    unsigned u = __builtin_bit_cast(unsigned, f);
    return (u16)((u + 0x7FFFu + ((u >> 16) & 1u)) >> 16);
}
__device__ __forceinline__ float bf2f(u16 h) {
    unsigned u = ((unsigned)h) << 16;
    return __builtin_bit_cast(float, u);
}

// async global->LDS, 16B/lane. dst wave-uniform; lane i lands at dst + i*16.
__device__ __forceinline__ void gload_lds16(const void* g, void* l) {
    __builtin_amdgcn_global_load_lds(
        (const __attribute__((address_space(1))) unsigned int*)g,
        (__attribute__((address_space(3))) unsigned int*)l,
        16, 0, 0);
}

__device__ __forceinline__ unsigned cvtpk(float a, float b) {
    unsigned r;
    asm volatile("v_cvt_pk_bf16_f32 %0, %1, %2" : "=v"(r) : "v"(a), "v"(b));
    return r;  // lo16 = bf16(a), hi16 = bf16(b)
}

// exchange: x' = [x_lo, y_lo(partner)], y' = [x_hi(partner), y_hi]
__device__ __forceinline__ void halfswap(unsigned& x, unsigned& y, bool hihalf) {
    const unsigned xs = (unsigned)__shfl_xor((int)x, 32);
    const unsigned ys = (unsigned)__shfl_xor((int)y, 32);
    const unsigned nx = hihalf ? ys : x;
    const unsigned ny = hihalf ? y : xs;
    x = nx; y = ny;
}

__device__ __forceinline__ short8 build_pfrag(float p0, float p1, float p2, float p3,
                                              float p4, float p5, float p6, float p7,
                                              bool hihalf) {
    unsigned x1 = cvtpk(p0, p1), y1 = cvtpk(p4, p5);
    unsigned x2 = cvtpk(p2, p3), y2 = cvtpk(p6, p7);
    halfswap(x1, y1, hihalf);
    halfswap(x2, y2, hihalf);
    union { unsigned u[4]; short8 s; } pk;
    pk.u[0] = x1; pk.u[1] = x2; pk.u[2] = y1; pk.u[3] = y2;
    return pk.s;
}

// ---------------------------------------------------------------------------
// One fused prep kernel for the CONCATENATED layout.
// acat [8192][1664]: cols 0:1152 = bf16(x); cols 1152:1664 filled by h12 GEMM.
// bcat [3584][1664]: rows 0:1152 = [Wq*kCexp | 0]; rows 1152:3456 =
//   [Wkv | up_w | pup_w]; rows 3456:3584 untouched (pad; feeds pad cols only).
// bq [3584]: 0 for q cols; (task>=4 ? up_b (+pup_b if task>=5) : 0) for kv.
// Zero block MUST be written every call (ws is not re-poisoned).
// ---------------------------------------------------------------------------
constexpr int P0 = 2359296;            // x -> acat strided        (rl 288 -> 416)
constexpr int P1 = P0 + 995328;        // Wqkv -> bcat strided     (rl 288 -> 416)
constexpr int P2 = P1 + 147456;        // zeros -> bcat[0:1152][288:416 f4]
constexpr int P3 = P2 + 147456;        // up_w -> bcat[1152+r][288+c]
constexpr int P4 = P3 + 147456;        // pup_w -> bcat[1152+r][352+c]
constexpr int P5 = P4 + 331776;        // Wproj
constexpr int P6 = P5 + 73728;         // down_w
constexpr int P7 = P6 + 73728;         // pdown_w
constexpr int P8 = P7 + 512;           // bd scalars
constexpr int P9 = P8 + 3584;          // bq scalars
constexpr int kQPart = 331776;         // Wqkv q-part f4 count
constexpr int kPrepGrid = P9 / 256;    // 16720 exactly

__global__ __launch_bounds__(256)
void prep_all(const float* __restrict__ x, const float* __restrict__ Wqkv,
              const float* __restrict__ Wproj,
              const float* __restrict__ down_w, const float* __restrict__ pdown_w,
              const float* __restrict__ up_w, const float* __restrict__ pup_w,
              const float* __restrict__ down_b, const float* __restrict__ pdown_b,
              const float* __restrict__ up_b, const float* __restrict__ pup_b,
              const int* __restrict__ task,
              u16* __restrict__ acat, u16* __restrict__ bcat,
              u16* __restrict__ wprjb, u16* __restrict__ wdownb,
              float* __restrict__ bd, float* __restrict__ bq)
{
    const int i = blockIdx.x * blockDim.x + threadIdx.x;
    auto cvt4s = [](const float* s, int j, float sc) {
        const float4 v = reinterpret_cast<const float4*>(s)[j];
        ushort4 o;
        o.x = f2bf(v.x * sc); o.y = f2bf(v.y * sc);
        o.z = f2bf(v.z * sc); o.w = f2bf(v.w * sc);
        return o;
    };
    if (i < P0) {
        const int r = i / 288, c = i - r * 288;
        reinterpret_cast<ushort4*>(acat)[r * 416 + c] = cvt4s(x, i, 1.f);
    } else if (i < P1) {
        const int j = i - P0;
        const float sc = (j < kQPart) ? kCexp : 1.f;   // softmax scale into Wq
        const int r = j / 288, c = j - r * 288;
        reinterpret_cast<ushort4*>(bcat)[r * 416 + c] = cvt4s(Wqkv, j, sc);
    } else if (i < P2) {
        const int j = i - P1, r = j >> 7, c = j & 127;
        reinterpret_cast<ushort4*>(bcat)[r * 416 + 288 + c] = ushort4{0, 0, 0, 0};
    } else if (i < P3) {
        const int j = i - P2, r = j >> 6, c = j & 63;
        reinterpret_cast<ushort4*>(bcat)[(1152 + r) * 416 + 288 + c] = cvt4s(up_w, j, 1.f);
    } else if (i < P4) {
        const int j = i - P3, r = j >> 6, c = j & 63;
        reinterpret_cast<ushort4*>(bcat)[(1152 + r) * 416 + 352 + c] = cvt4s(pup_w, j, 1.f);
    } else if (i < P5) {
        reinterpret_cast<ushort4*>(wprjb)[i - P4] = cvt4s(Wproj, i - P4, 1.f);
    } else if (i < P6) {
        reinterpret_cast<ushort4*>(wdownb)[i - P5] = cvt4s(down_w, i - P5, 1.f);
    } else if (i < P7) {
        reinterpret_cast<ushort4*>(wdownb)[73728 + (i - P6)] = cvt4s(pdown_w, i - P6, 1.f);
    } else if (i < P8) {
        const int j = i - P7;
        bd[j] = (j < 256) ? down_b[j] : pdown_b[j - 256];
    } else {
        const int j = i - P8;
        float v = 0.f;
        if (j >= 1152 && j < 3456 && *task >= 4) {
            v = up_b[j - 1152];
            if (*task >= 5) v += pup_b[j - 1152];
        }
        bq[j] = v;
    }
}

// ---------------------------------------------------------------------------
// 256x256 tile GEMM, 8-phase template (T3+T4) — CONCATENATED qkv:
// C = acat @ bcat^T + bq. Runtime K by task: 1664 / 1408 / 1152 (excludes
// pup / both prefixes exactly). Replaces qkv GEMM + up GEMM + ACCUM pass.
// ---------------------------------------------------------------------------
__global__ __launch_bounds__(512, 2)
void gemm8p(const u16* __restrict__ A, const u16* __restrict__ Bw,
            const float* __restrict__ bias, u16* __restrict__ C,
            const int* __restrict__ taskp)
{
    extern __shared__ char lds[];   // [A0 32K][A1 32K][B0 32K][B1 32K]

    const int tk = *taskp;
    const int K = (tk >= 5) ? 1664 : ((tk >= 4) ? 1408 : 1152);
    const int lda = kKC, ldb = kKC, ldc = kQS;

    const int tid  = threadIdx.x;
    const int lane = tid & 63;
    const int wid  = tid >> 6;
    const int wm   = wid >> 2;             // 0..1 : 128-row half
    const int wn   = wid & 3;              // 0..3 : 64-col quarter
    const int bm   = blockIdx.x * 256;
    const int bn   = blockIdx.y * 256;
    const int l15  = lane & 15;
    const int kq   = lane >> 4;            // 0..3

    int srow[4], scol[4], sdst[4];
#pragma unroll
    for (int i = 0; i < 4; ++i) {
        const int id = i * 512 + tid;
        srow[i] = id >> 3;
        const int s = id & 7;
        scol[i] = (s ^ (srow[i] & 7)) * 8;          // pre-swizzled source col (elems)
        sdst[i] = (i * 512 + wid * 64) * 16;        // wave-uniform LDS byte base
    }

    auto stage_pair = [&](int buf, int kt, int i) {
        const u16* ag = A  + (size_t)bm * lda + kt * 64;
        const u16* bg = Bw + (size_t)bn * ldb + kt * 64;
        gload_lds16(ag + (size_t)srow[i] * lda + scol[i], lds + buf * 32768 + sdst[i]);
        gload_lds16(bg + (size_t)srow[i] * ldb + scol[i], lds + 65536 + buf * 32768 + sdst[i]);
    };

    f32x4 acc[8][4] = {};
    const int nt = K >> 6;

#pragma unroll
    for (int i = 0; i < 4; ++i) stage_pair(0, 0, i);

    for (int t = 0; t < nt; ++t) {
        const char* Ab = lds + (t & 1) * 32768;
        const char* Bb = lds + 65536 + (t & 1) * 32768;
        const bool nxt = (t + 1 < nt);
        const int nb = (t + 1) & 1;

        short8 af[4], bf[4];

        auto rdA = [&](int mh, int ks) {
#pragma unroll
            for (int mi = 0; mi < 4; ++mi) {
                const int row = wm * 128 + mh * 64 + mi * 16 + l15;
                af[mi] = *reinterpret_cast<const short8*>(
                    Ab + row * 128 + (((ks * 4 + kq) ^ (row & 7)) * 16));
            }
        };
        auto rdB = [&](int ks) {
#pragma unroll
            for (int ni = 0; ni < 4; ++ni) {
                const int row = wn * 64 + ni * 16 + l15;
                bf[ni] = *reinterpret_cast<const short8*>(
                    Bb + row * 128 + (((ks * 4 + kq) ^ (row & 7)) * 16));
            }
        };
        auto mfma16 = [&](int mh) {
            asm volatile("s_waitcnt lgkmcnt(0)" ::: "memory");
            __builtin_amdgcn_sched_barrier(0);
            __builtin_amdgcn_s_setprio(1);
#pragma unroll
            for (int mi = 0; mi < 4; ++mi)
#pragma unroll
                for (int ni = 0; ni < 4; ++ni)
                    acc[mh * 4 + mi][ni] = __builtin_amdgcn_mfma_f32_16x16x32_bf16(
                        af[mi], bf[ni], acc[mh * 4 + mi][ni], 0, 0, 0);
            __builtin_amdgcn_s_setprio(0);
            asm volatile("" ::: "memory");
            __builtin_amdgcn_s_barrier();
            asm volatile("" ::: "memory");
        };

        // ---- phase 0: publish buf t; counted vmcnt; quadrant (mh=0, ks=0)
        if (nxt) { stage_pair(nb, t + 1, 0); stage_pair(nb, t + 1, 1); }
        if (nxt) asm volatile("s_waitcnt vmcnt(4)" ::: "memory");
        else     asm volatile("s_waitcnt vmcnt(0)" ::: "memory");
        __builtin_amdgcn_sched_barrier(0);
        __builtin_amdgcn_s_barrier();
        asm volatile("" ::: "memory");
        rdB(0); rdA(0, 0);
        mfma16(0);

        // ---- phase 1: (mh=1, ks=0), issue remaining prefetch
        if (nxt) { stage_pair(nb, t + 1, 2); stage_pair(nb, t + 1, 3); }
        rdA(1, 0);
        mfma16(1);

        // ---- phase 2: (mh=0, ks=1)
        rdB(1); rdA(0, 1);
        mfma16(0);

        // ---- phase 3: (mh=1, ks=1)
        rdA(1, 1);
        mfma16(1);
    }

#pragma unroll
    for (int mg = 0; mg < 8; ++mg) {
#pragma unroll
        for (int ni = 0; ni < 4; ++ni) {
            const int col = bn + wn * 64 + ni * 16 + l15;
            const float bv = bias[col];
#pragma unroll
            for (int r = 0; r < 4; ++r) {
                const int row = bm + wm * 128 + mg * 16 + kq * 4 + r;
                C[(size_t)row * ldc + col] = f2bf(acc[mg][ni][r] + bv);
            }
        }
    }
}

// ---------------------------------------------------------------------------
// 128x128 m97-structure GEMM (h12, proj).
// ---------------------------------------------------------------------------
template<bool TANH, bool BIAS, bool OUT_BF16>
__global__ __launch_bounds__(256)
void gemm_mfma(const u16* __restrict__ A, const u16* __restrict__ Bw,
               const float* __restrict__ bias, void* __restrict__ Cv,
               int K, int lda, int ldb, int ldc)
{
    __shared__ u16 As[2][128 * 64];
    __shared__ u16 Bs[2][128 * 64];

    const int tid  = threadIdx.x;
    const int lane = tid & 63;
    const int wv   = tid >> 6;
    const int wr   = (wv >> 1) * 64;
    const int wc   = (wv & 1) * 64;
    const int bm   = blockIdx.x * 128;
    const int bn   = blockIdx.y * 128;

    f32x4 acc[4][4] = {};

    const int srow = tid >> 3;
    const int sslt = tid & 7;

    auto stage = [&](int buf, int k0) {
        const u16* ab = A  + (size_t)bm * lda + k0;
        const u16* bb = Bw + (size_t)bn * ldb + k0;
#pragma unroll
        for (int i = 0; i < 4; ++i) {
            const int row = i * 32 + srow;
            gload_lds16(ab + (size_t)row * lda + sslt * 8,
                        (char*)&As[buf][0] + (i * 256 + (tid & 192)) * 16);
        }
#pragma unroll
        for (int i = 0; i < 4; ++i) {
            const int row = i * 32 + srow;
            gload_lds16(bb + (size_t)row * ldb + sslt * 8,
                        (char*)&Bs[buf][0] + (i * 256 + (tid & 192)) * 16);
        }
    };

    stage(0, 0);
    const int nk = K >> 6;
    for (int kt = 0; kt < nk; ++kt) {
        __syncthreads();
        if (kt + 1 < nk) stage((kt + 1) & 1, (kt + 1) * 64);
        const u16* as = &As[kt & 1][0];
        const u16* bs = &Bs[kt & 1][0];
#pragma unroll
        for (int ks = 0; ks < 2; ++ks) {
            short8 af[4], bf[4];
#pragma unroll
            for (int mi = 0; mi < 4; ++mi) {
                const int row = wr + mi * 16 + (lane & 15);
                af[mi] = *reinterpret_cast<const short8*>(as + row * 64 + ks * 32 + (lane >> 4) * 8);
            }
#pragma unroll
            for (int ni = 0; ni < 4; ++ni) {
                const int row = wc + ni * 16 + (lane & 15);
                bf[ni] = *reinterpret_cast<const short8*>(bs + row * 64 + ks * 32 + (lane >> 4) * 8);
            }
#pragma unroll
            for (int mi = 0; mi < 4; ++mi)
#pragma unroll
                for (int ni = 0; ni < 4; ++ni)
                    acc[mi][ni] = __builtin_amdgcn_mfma_f32_16x16x32_bf16(
                        af[mi], bf[ni], acc[mi][ni], 0, 0, 0);
        }
    }

#pragma unroll
    for (int mi = 0; mi < 4; ++mi) {
#pragma unroll
        for (int ni = 0; ni < 4; ++ni) {
            const int col = bn + wc + ni * 16 + (lane & 15);
            const float bv = BIAS ? bias[col] : 0.f;
#pragma unroll
            for (int r = 0; r < 4; ++r) {
                const int row = bm + wr + mi * 16 + (lane >> 4) * 4 + r;
                float v = acc[mi][ni][r] + bv;
                if (TANH) v = tanhf(v);
                if (OUT_BF16) {
                    ((u16*)Cv)[(size_t)row * ldc + col] = f2bf(v);
                } else {
                    ((float*)Cv)[(size_t)row * ldc + col] = v;
                }
            }
        }
    }
}

// ---------------------------------------------------------------------------
// V transpose: qkv v-part [tok][d] -> vt[(b*9+h)*128 + d][tok] (coalesced).
// ---------------------------------------------------------------------------
__global__ __launch_bounds__(256)
void transpose_v(const u16* __restrict__ qkv, u16* __restrict__ vt)
{
    __shared__ u16 t[64][136];
    const int bh = blockIdx.x, b = bh / kHeads, h = bh - b * kHeads;
    const int n0 = blockIdx.y * 64;
    const int tid = threadIdx.x;
#pragma unroll
    for (int it = 0; it < 4; ++it) {
        const int I = it * 256 + tid, tok = I >> 4, s = I & 15;
        *reinterpret_cast<short8*>(&t[tok][s * 8]) =
            *reinterpret_cast<const short8*>(
                qkv + (size_t)(b * kN + n0 + tok) * kQS + 2304 + h * 128 + s * 8);
    }
    __syncthreads();
#pragma unroll
    for (int it = 0; it < 8; ++it) {
        const int I = it * 256 + tid;
        const int d = I >> 4, tk = (I & 15) * 4;
        ushort4 v;
        v.x = t[tk + 0][d]; v.y = t[tk + 1][d];
        v.z = t[tk + 2][d]; v.w = t[tk + 3][d];
        *reinterpret_cast<ushort4*>(vt + (size_t)(bh * 128 + d) * kN + n0 + tk) = v;
    }
}

// ---------------------------------------------------------------------------
// MFMA flash attention, INTRA-BLOCK KV-SPLIT (r13 configuration — measured
// 81 us @ 21.6% occupancy, VGPR 84). Unchanged.
// ---------------------------------------------------------------------------
__global__ __launch_bounds__(256)
void attn_mfma(const u16* __restrict__ qkv, const u16* __restrict__ vt,
               u16* __restrict__ out)
{
    __shared__ u16 Ks[2][32 * 128];   // [kvhalf][tok][d] swizzled, 8 KB each
    __shared__ u16 Vs[2][128 * 32];   // [kvhalf][d][tok] swizzled, 8 KB each

    const int bh = blockIdx.x, b = bh / kHeads, h = bh - b * kHeads;
    const int tid = threadIdx.x, lane = tid & 63, wv = tid >> 6;
    const int lo5 = lane & 31;
    const bool hihalf = (lane >= 32);
    const int hi = hihalf ? 1 : 0;
    const int qh = wv >> 1;                 // q half within the 64-row block
    const int kh = wv & 1;                  // kv half (tokens kh*512 ..)
    const int q0 = blockIdx.y * 64 + qh * 32;

    // Q frags (B-operand): q = lo5, d = f*16 + hi*8 + e (pre-scaled by kCexp)
    const u16* qp = qkv + (size_t)(b * kN + q0 + lo5) * kQS + h * 128;
    short8 qf[8];
#pragma unroll
    for (int f = 0; f < 8; ++f)
        qf[f] = *reinterpret_cast<const short8*>(qp + f * 16 + hi * 8);

    // staging offsets (pre-swizzled global source, linear LDS dst).
    int koff[2], voff[2];
#pragma unroll
    for (int j = 0; j < 2; ++j) {
        const int I = j * 256 + tid;        // 0..511
        const int tok = I >> 4, s = I & 15;
        koff[j] = tok * kQS + ((s ^ (tok & 7)) * 8);
        const int d = I >> 2, sv = I & 3;
        voff[j] = d * kN + ((sv ^ (d & 3)) * 8);
    }
    const u16* kbase = qkv + (size_t)b * kN * kQS + kDim + h * 128;
    const u16* vbase = vt + (size_t)bh * 128 * kN;

    f32x16 o[4] = {};
    float l = 0.f;

    for (int t = 0; t < 16; ++t) {
        __syncthreads();   // prev iteration's readers done
#pragma unroll
        for (int hh = 0; hh < 2; ++hh) {
            const int kt = hh * 512 + t * 32;
#pragma unroll
            for (int j = 0; j < 2; ++j) {
                gload_lds16(kbase + (size_t)kt * kQS + koff[j],
                            (char*)&Ks[hh][0] + (j * 256 + wv * 64) * 16);
                gload_lds16(vbase + kt + voff[j],
                            (char*)&Vs[hh][0] + (j * 256 + wv * 64) * 16);
            }
        }
        __syncthreads();   // vmcnt(0) drained by compiler before barrier

        const char* ks = (const char*)&Ks[kh][0];
        const char* vs = (const char*)&Vs[kh][0];

        // S^T = K Q^T : A = K rows (32 ktok), B = Q(log2 units). col(q)=lo5
        f32x16 s0 = {};
        __builtin_amdgcn_s_setprio(1);
#pragma unroll
        for (int f = 0; f < 8; ++f) {
            const short8 ka = *reinterpret_cast<const short8*>(
                ks + lo5 * 256 + (((f * 2 + hi) * 16) ^ ((lo5 & 7) << 4)));
            s0 = __builtin_amdgcn_mfma_f32_32x32x16_bf16(ka, qf[f], s0, 0, 0, 0);
        }
        __builtin_amdgcn_s_setprio(0);

        // fixed-zero-max softmax: p = exp2(s) directly
        float rsum = 0.f;
#pragma unroll
        for (int r = 0; r < 16; ++r) { s0[r] = exp2f(s0[r]); rsum += s0[r]; }
        rsum += __shfl_xor(rsum, 32);
        l += rsum;

        // P frags (B-operand, k = hi*8+e per 16-ktok chunk)
        short8 pf[2];
        pf[0] = build_pfrag(s0[0], s0[1], s0[2], s0[3], s0[4], s0[5], s0[6], s0[7], hihalf);
        pf[1] = build_pfrag(s0[8], s0[9], s0[10], s0[11], s0[12], s0[13], s0[14], s0[15], hihalf);

        // O^T += V^T P : A = V^T rows (d, 32-tok cols), B = P^T. col(q)=lo5
        __builtin_amdgcn_s_setprio(1);
#pragma unroll
        for (int dt = 0; dt < 4; ++dt) {
            const int drow = dt * 32 + lo5;
#pragma unroll
            for (int c = 0; c < 2; ++c) {
                const short8 va = *reinterpret_cast<const short8*>(
                    vs + drow * 64 + (((c * 2 + hi) * 16) ^ ((drow & 3) << 4)));
                o[dt] = __builtin_amdgcn_mfma_f32_32x32x16_bf16(va, pf[c], o[dt], 0, 0, 0);
            }
        }
        __builtin_amdgcn_s_setprio(0);
    }

    // ---- pair combine through dead LDS (waves kh=1 -> kh=0), then output.
    __syncthreads();   // all waves done reading Ks/Vs
    char* exch = (char*)&Ks[0][0];
    float* ls  = (float*)&Vs[0][0];
    if (kh == 1) {
#pragma unroll
        for (int dt = 0; dt < 4; ++dt) {
#pragma unroll
            for (int rg = 0; rg < 4; ++rg) {
                const int kb = (dt * 4 + rg) * 8;     // 8-byte chunk index
                ushort4 w;
                w.x = f2bf(o[dt][rg * 4 + 0]);
                w.y = f2bf(o[dt][rg * 4 + 1]);
                w.z = f2bf(o[dt][rg * 4 + 2]);
                w.w = f2bf(o[dt][rg * 4 + 3]);
                *reinterpret_cast<ushort4*>(
                    exch + qh * 8192 + lane * 128 + (kb ^ ((lane & 7) << 3))) = w;
            }
        }
        if (!hihalf) ls[qh * 32 + lo5] = l;
    }
    __syncthreads();
    if (kh == 0) {
        const float inv = 1.f / (l + ls[qh * 32 + lo5]);
        u16* op = out + (size_t)(b * kN + q0 + lo5) * kDim + h * 128;
#pragma unroll
        for (int dt = 0; dt < 4; ++dt) {
#pragma unroll
            for (int rg = 0; rg < 4; ++rg) {
                const int kb = (dt * 4 + rg) * 8;
                const ushort4 pv = *reinterpret_cast<const ushort4*>(
                    exch + qh * 8192 + lane * 128 + (kb ^ ((lane & 7) << 3)));
                const int d0 = dt * 32 + rg * 8 + hi * 4;
                ushort4 v;
                v.x = f2bf((o[dt][rg * 4 + 0] + bf2f(pv.x)) * inv);
                v.y = f2bf((o[dt][rg * 4 + 1] + bf2f(pv.y)) * inv);
                v.z = f2bf((o[dt][rg * 4 + 2] + bf2f(pv.z)) * inv);
                v.w = f2bf((o[dt][rg * 4 + 3] + bf2f(pv.w)) * inv);
                *reinterpret_cast<ushort4*>(op + d0) = v;
            }
        }
    }
}

}  // namespace

extern "C" void kernel_launch(void* const* d_in, const int* in_sizes, int n_in,
                              void* d_out, int out_size, void* d_ws, size_t ws_size,
                              hipStream_t stream)
{
    const float* x       = (const float*)d_in[0];
    const float* Wqkv    = (const float*)d_in[1];
    const float* Wproj   = (const float*)d_in[2];
    const float* bproj   = (const float*)d_in[3];
    const float* down_w  = (const float*)d_in[4];
    const float* down_b  = (const float*)d_in[5];
    const float* up_w    = (const float*)d_in[6];
    const float* up_b    = (const float*)d_in[7];
    const float* pdown_w = (const float*)d_in[8];
    const float* pdown_b = (const float*)d_in[9];
    const float* pup_w   = (const float*)d_in[10];
    const float* pup_b   = (const float*)d_in[11];
    const int*   task    = (const int*)d_in[12];

    // ws layout (u16 elements). vt aliases acat (acat dead after merged GEMM).
    u16* acat   = (u16*)d_ws;                          // [8192][1664] = 13,631,488
    u16* bcat   = acat   + (size_t)kM * kKC;           // [3584][1664] =  5,963,776
    u16* wprjb  = bcat   + (size_t)kQS * kKC;          //  1,327,104
    u16* wdownb = wprjb  + (size_t)kDim * kDim;        //  [512][1152]
    u16* qkvb   = wdownb + (size_t)512 * kDim;         //  [8192][3584] padded
    u16* aob    = qkvb   + (size_t)kM * kQS;           //  [8192][1152]
    float* bd   = (float*)(aob + (size_t)kM * kDim);   //  512 f32
    float* bq   = bd + 512;                            //  3584 f32
    float* out  = (float*)d_out;
    u16* vt = acat;

    prep_all<<<kPrepGrid, 256, 0, stream>>>(
        x, Wqkv, Wproj, down_w, pdown_w, up_w, pup_w,
        down_b, pdown_b, up_b, pup_b, task,
        acat, bcat, wprjb, wdownb, bd, bq);

    hipFuncSetAttribute(reinterpret_cast<const void*>(&gemm8p),
                        hipFuncAttributeMaxDynamicSharedMemorySize, 131072);

    // h12 = tanh(x @ [down_w;pdown_w]^T + bd)  ->  acat cols 1152:1664
    gemm_mfma<true, true, true><<<dim3(kM / 128, 4), 256, 0, stream>>>(
        acat, wdownb, bd, acat + kDim, kDim, kKC, kDim, kKC);

    // qkv = [x|h12] @ [[Wq,0];[Wkv,Wup]]^T + [0|bu]  (one merged GEMM;
    // runtime K = 1664/1408/1152 gates the prefix contributions by task)
    gemm8p<<<dim3(kM / 256, kQS / 256), 512, 131072, stream>>>(
        acat, bcat, bq, qkvb, task);

    // vt[(b*9+h)*128+d][tok] = V  (coalesced; vt aliases dead acat)
    transpose_v<<<dim3(kB * kHeads, kN / 64), 256, 0, stream>>>(qkvb, vt);

    // attention (intra-block KV-split, 1152 blocks, 32 KiB static LDS)
    attn_mfma<<<dim3(kB * kHeads, kN / 64), 256, 0, stream>>>(qkvb, vt, aob);

    // out = attn_out @ Wproj^T + bproj  (fp32)
    gemm_mfma<false, true, false><<<dim3(kM / 128, 9), 256, 0, stream>>>(
        aob, wprjb, bproj, out, kDim, kDim, kDim, kDim);

    // second output: down_w passthrough
    hipMemcpyAsync(out + (size_t)kM * kDim, down_w,
                   (size_t)kMid * kDim * sizeof(float),
                   hipMemcpyDeviceToDevice, stream);
}